// Round 7
// baseline (244.602 us; speedup 1.0000x reference)
//
#include <hip/hip_runtime.h>
#include <stdint.h>

#define N 8192
#define C 512
#define BM 64                         /* rows per block (4 waves, same rows) */
#define BN 128
#define BKF 128                       /* fp8 bytes per K-tile */
#define NSPLIT 8
#define COLS_PER_SPLIT (N / NSPLIT)   /* 1024 */
#define CT (COLS_PER_SPLIT / BN)      /* 8 */
#define NRB (N / BM)                  /* 128 row-bands */
#define GRID_GEMM (NRB * NSPLIT)      /* 1024 blocks, 2/CU, 2 rounds */
#define INV_T 14.285714285714286f
#define SCALE2 20.60992915555662f     /* INV_T * log2(e): base-2 logits */
#define LN2F 0.6931471805599453f

typedef __attribute__((ext_vector_type(4)))  int   i32x4;
typedef __attribute__((ext_vector_type(8)))  int   i32x8;
typedef __attribute__((ext_vector_type(16))) float f32x16;

// ---- fused prep: fp32 -> fp8 e4m3 (HW cvt) for X and Y + exact fp32 pos ----
__global__ __launch_bounds__(256) void prep_kernel(const float* __restrict__ X,
                                                   const float* __restrict__ Y,
                                                   unsigned char* __restrict__ Xf8,
                                                   unsigned char* __restrict__ Yf8,
                                                   float* __restrict__ pos,
                                                   int* __restrict__ cnt,
                                                   float* __restrict__ out) {
  if (blockIdx.x == 0) {
    if (threadIdx.x < NRB) cnt[threadIdx.x] = 0;
    if (threadIdx.x == 128) *out = 0.0f;
  }
  const int wave = threadIdx.x >> 6;
  const int lane = threadIdx.x & 63;
  const int row = blockIdx.x * 4 + wave;
  const float4* xr = (const float4*)(X + (size_t)row * C) + lane * 2;
  const float4* yr = (const float4*)(Y + (size_t)row * C) + lane * 2;
  float4 x0 = xr[0], x1 = xr[1];
  float4 y0 = yr[0], y1 = yr[1];
  float s = x0.x * y0.x + x0.y * y0.y + x0.z * y0.z + x0.w * y0.w
          + x1.x * y1.x + x1.y * y1.y + x1.z * y1.z + x1.w * y1.w;
  int2 ox, oy;
  ox.x = __builtin_amdgcn_cvt_pk_fp8_f32(x0.x, x0.y, 0, false);
  ox.x = __builtin_amdgcn_cvt_pk_fp8_f32(x0.z, x0.w, ox.x, true);
  ox.y = __builtin_amdgcn_cvt_pk_fp8_f32(x1.x, x1.y, 0, false);
  ox.y = __builtin_amdgcn_cvt_pk_fp8_f32(x1.z, x1.w, ox.y, true);
  oy.x = __builtin_amdgcn_cvt_pk_fp8_f32(y0.x, y0.y, 0, false);
  oy.x = __builtin_amdgcn_cvt_pk_fp8_f32(y0.z, y0.w, oy.x, true);
  oy.y = __builtin_amdgcn_cvt_pk_fp8_f32(y1.x, y1.y, 0, false);
  oy.y = __builtin_amdgcn_cvt_pk_fp8_f32(y1.z, y1.w, oy.y, true);
  ((int2*)(Xf8 + (size_t)row * C))[lane] = ox;
  ((int2*)(Yf8 + (size_t)row * C))[lane] = oy;
#pragma unroll
  for (int off = 32; off >= 1; off >>= 1) s += __shfl_xor(s, off);
  if (lane == 0) pos[row] = s * INV_T;
}

// ---- main: MX-scaled fp8 MFMA + base-2 online lse + fused combine ----
// v7 = v6 geometry (wave = 64 rows x 32 cols, mr=2 -> 1.0 ds_read/MFMA,
// acc = 32 regs) with the spill-corruption hazard removed: A loaded via
// plain compiler-visible i32x8 derefs straight into aF (no temp+pack, peak
// demand ~250), and the prologue drain is a real __syncthreads() so the
// compiler's waitcnt pass knows its loads are done pre-loop. In-loop VMEM
// remains ONLY the global_load_lds builtins -> counted vmcnt(4) intact.
__global__ __launch_bounds__(256, 2) void gemm_lse_kernel(const unsigned char* __restrict__ Xf8,
                                                          const unsigned char* __restrict__ Yf8,
                                                          float2* __restrict__ partials,
                                                          const float* __restrict__ pos,
                                                          int* __restrict__ cnt,
                                                          float* __restrict__ out) {
  __shared__ unsigned char Bs[2][BN][BKF];   // 32 KB double-buffered B k-tile
  __shared__ float wsum[4];
  __shared__ int mflag;

  const int tid = threadIdx.x;
  const int bx = blockIdx.x;
  const int split = bx & (NSPLIT - 1);      // XCD = bx%8 -> Y-slice L2 local
  const int rb = bx >> 3;                   // 0..127
  const int row0 = rb * BM;
  const int colbase = split * COLS_PER_SPLIT;

  const int w = tid >> 6;                   // wave 0..3 = col-slice wc
  const int lane = tid & 63;
  const int lrow = lane & 31;
  const int h = lane >> 5;                  // k-half selector
  const int swz = lrow & 7;
  const int brow = w * 32 + lrow;           // this wave's B rows in Bs

  // ---- A: 2 rowsets x full K=512, straight into fragment regs ----
  i32x8 aF0[8], aF1[8];
  {
    const unsigned char* a0 = Xf8 + (size_t)(row0 + lrow) * C + h * 32;
#pragma unroll
    for (int kk = 0; kk < 8; ++kk) {
      aF0[kk] = *(const i32x8*)(a0 + kk * 64);
      aF1[kk] = *(const i32x8*)(a0 + (size_t)32 * C + kk * 64);
    }
  }

  // B staging-lane invariants (pre-swizzled global source, linear LDS dest)
  const int r_base = tid >> 3;              // row within 32-row group
  const int p = tid & 7;
  const int j = p ^ (r_base & 7);

  auto stageB = [&](int buf, int col0, int k0) {
#pragma unroll
    for (int i = 0; i < 4; ++i) {
      const int r = i * 32 + r_base;
      const unsigned char* gb = Yf8 + (size_t)(col0 + r) * C + k0 * BKF + j * 16;
      uint32_t loff = (uint32_t)((i * 256 + (tid & ~63)) * 16);
      __builtin_amdgcn_global_load_lds(
          (const __attribute__((address_space(1))) uint32_t*)(uintptr_t)gb,
          (__attribute__((address_space(3))) uint32_t*)(uintptr_t)((char*)&Bs[buf][0][0] + loff),
          16, 0, 0);
    }
  };

  // prologue: stage (ct=0,k0=0), then ONE real __syncthreads(): the compiler
  // emits s_waitcnt vmcnt(0) lgkmcnt(0) here, draining the A loads (which it
  // tracks) and the stage loads in one shot, pre-loop.
  stageB(0, colbase, 0);
  __syncthreads();
  __builtin_amdgcn_sched_barrier(0);

  float m0[16], l0[16], m1[16], l1[16];     // base-2 online state
#pragma unroll
  for (int s = 0; s < 16; ++s) {
    m0[s] = -INFINITY; l0[s] = 0.0f;
    m1[s] = -INFINITY; l1[s] = 0.0f;
  }

  for (int ct = 0; ct < CT; ++ct) {
    f32x16 acc0, acc1;
#pragma unroll
    for (int e = 0; e < 16; ++e) { acc0[e] = 0.0f; acc1[e] = 0.0f; }

#pragma unroll
    for (int k0 = 0; k0 < 4; ++k0) {      // tile (ct,k0) lives in Bs[k0&1]
      const int nct = (k0 == 3) ? ((ct + 1) & (CT - 1)) : ct;
      const int nk0 = (k0 + 1) & 3;
      stageB((k0 + 1) & 1, colbase + nct * BN, nk0);
      __builtin_amdgcn_sched_barrier(0);
      asm volatile("s_waitcnt vmcnt(4)" ::: "memory");   // counted, never 0
      __builtin_amdgcn_s_barrier();
      __builtin_amdgcn_sched_barrier(0);

      __builtin_amdgcn_s_setprio(1);
      const unsigned char* bbase = &Bs[k0 & 1][brow][0];
#pragma unroll
      for (int s = 0; s < 2; ++s) {       // two K=64 steps per 128B segment
        const int kk = 2 * k0 + s;
        const int c0 = 4 * s + 2 * h;
        i32x8 bf;
        *(i32x4*)&bf         = *(const i32x4*)(bbase + ((c0    ) ^ swz) * 16);
        *(((i32x4*)&bf) + 1) = *(const i32x4*)(bbase + ((c0 + 1) ^ swz) * 16);
        acc0 = __builtin_amdgcn_mfma_scale_f32_32x32x64_f8f6f4(
            aF0[kk], bf, acc0, 0, 0, 0, 127, 0, 127);
        acc1 = __builtin_amdgcn_mfma_scale_f32_32x32x64_f8f6f4(
            aF1[kk], bf, acc1, 0, 0, 0, 127, 0, 127);
      }
      __builtin_amdgcn_s_setprio(0);
      __builtin_amdgcn_sched_barrier(0);
      __builtin_amdgcn_s_barrier();       // reads done before next overwrite
      __builtin_amdgcn_sched_barrier(0);
    }

    // per-lane base-2 online update (1 col per lane per ct)
#pragma unroll
    for (int r = 0; r < 16; ++r) {
      float u0 = acc0[r] * SCALE2;
      float n0 = fmaxf(m0[r], u0);
      l0[r] = l0[r] * exp2f(m0[r] - n0) + exp2f(u0 - n0);
      m0[r] = n0;
      float u1 = acc1[r] * SCALE2;
      float n1 = fmaxf(m1[r], u1);
      l1[r] = l1[r] * exp2f(m1[r] - n1) + exp2f(u1 - n1);
      m1[r] = n1;
    }
  }

  // drain the dangling wrap-prefetch (it targets Bs[0]!) before Bs reuse
  asm volatile("s_waitcnt vmcnt(0)" ::: "memory");

  // merge across the 32 lanes (cols) sharing each row-set
#pragma unroll
  for (int r = 0; r < 16; ++r) {
    float ma = m0[r], la = l0[r], mb = m1[r], lb = l1[r];
#pragma unroll
    for (int off = 1; off < 32; off <<= 1) {
      float mo = __shfl_xor(ma, off), lo = __shfl_xor(la, off);
      float mn = fmaxf(ma, mo);
      la = la * exp2f(ma - mn) + lo * exp2f(mo - mn);
      ma = mn;
      float mo2 = __shfl_xor(mb, off), lo2 = __shfl_xor(lb, off);
      float mn2 = fmaxf(mb, mo2);
      lb = lb * exp2f(mb - mn2) + lo2 * exp2f(mo2 - mn2);
      mb = mn2;
    }
    m0[r] = ma; l0[r] = la; m1[r] = mb; l1[r] = lb;
  }

  __syncthreads();                          // all waves past vmcnt(0): Bs dead
  // cross-wave (wc) merge through 2 KB of dead Bs space
  float2* mb2 = (float2*)&Bs[0][0][0];      // [wc][ar][h][r] = 256 float2
  if (lrow == 0) {
#pragma unroll
    for (int r = 0; r < 16; ++r) {
      mb2[((w * 2 + 0) * 2 + h) * 16 + r] = make_float2(m0[r], l0[r]);
      mb2[((w * 2 + 1) * 2 + h) * 16 + r] = make_float2(m1[r], l1[r]);
    }
  }
  __syncthreads();
  if (tid < BM) {                           // one thread per row
    const int ar = tid >> 5;
    const int rl = tid & 31;                // row_local = (r&3)+8*(r>>2)+4*h
    const int hI = (rl >> 2) & 1;
    const int rI = (rl & 3) + 4 * (rl >> 3);
    float M = -INFINITY, L = 0.0f;
#pragma unroll
    for (int wcI = 0; wcI < 4; ++wcI) {
      float2 pr = mb2[((wcI * 2 + ar) * 2 + hI) * 16 + rI];
      float mn = fmaxf(M, pr.x);
      L = L * exp2f(M - mn) + pr.y * exp2f(pr.x - mn);
      M = mn;
    }
    partials[(size_t)split * N + (row0 + tid)] = make_float2(M, L);
  }

  // ---- fused combine: last block for this rb merges all NSPLIT partials ----
  __syncthreads();
  if (tid == 0) {
    __threadfence();
    int old = atomicAdd(&cnt[rb], 1);
    mflag = (old == NSPLIT - 1) ? 1 : 0;
  }
  __syncthreads();
  if (mflag) {
    __threadfence();
    float v = 0.0f;
    if (tid < BM) {
      const int row = row0 + tid;
      float M = -INFINITY, L = 0.0f;
#pragma unroll
      for (int s = 0; s < NSPLIT; ++s) {
        float2 pr = partials[(size_t)s * N + row];
        float mn = fmaxf(M, pr.x);
        L = L * exp2f(M - mn) + pr.y * exp2f(pr.x - mn);
        M = mn;
      }
      v = LN2F * (M + log2f(L)) - pos[row];
    }
#pragma unroll
    for (int off = 32; off >= 1; off >>= 1) v += __shfl_xor(v, off);
    if (lane == 0) wsum[w] = v;
    __syncthreads();
    if (tid == 0) atomicAdd(out, wsum[0] + wsum[1] + wsum[2] + wsum[3]);
  }
}

extern "C" void kernel_launch(void* const* d_in, const int* in_sizes, int n_in,
                              void* d_out, int out_size, void* d_ws, size_t ws_size,
                              hipStream_t stream) {
  const float* X = (const float*)d_in[0];
  const float* Y = (const float*)d_in[1];
  float* out = (float*)d_out;

  // workspace: Xf8 (4MB) | Yf8 (4MB) | partials (512KB) | pos (32KB) | cnt
  char* w = (char*)d_ws;
  unsigned char* Xf8 = (unsigned char*)w;
  unsigned char* Yf8 = Xf8 + (size_t)N * C;
  float2* partials = (float2*)(Yf8 + (size_t)N * C);
  float* pos = (float*)((char*)partials + (size_t)NSPLIT * N * sizeof(float2));
  int* cnt = (int*)(pos + N);

  prep_kernel<<<N / 4, 256, 0, stream>>>(X, Y, Xf8, Yf8, pos, cnt, out);
  gemm_lse_kernel<<<GRID_GEMM, 256, 0, stream>>>(Xf8, Yf8, partials, pos, cnt, out);
}

// Round 8
// 219.426 us; speedup vs baseline: 1.1147x; 1.1147x over previous
//
#include <hip/hip_runtime.h>
#include <stdint.h>

#define N 8192
#define C 512
#define BM 64                         /* rows per block (4 waves, same rows) */
#define BN 128
#define BKF 128                       /* fp8 bytes per K-tile */
#define NSPLIT 8
#define COLS_PER_SPLIT (N / NSPLIT)   /* 1024 */
#define CT (COLS_PER_SPLIT / BN)      /* 8 */
#define NRB (N / BM)                  /* 128 row-bands */
#define GRID_GEMM (NRB * NSPLIT)      /* 1024 blocks, 2/CU, 2 rounds */
#define INV_T 14.285714285714286f
#define SCALE2 20.60992915555662f     /* INV_T * log2(e): base-2 logits */
#define LN2F 0.6931471805599453f

typedef __attribute__((ext_vector_type(4)))  int   i32x4;
typedef __attribute__((ext_vector_type(8)))  int   i32x8;
typedef __attribute__((ext_vector_type(16))) float f32x16;

// ---- fused prep: fp32 -> fp8 e4m3 (HW cvt) for X and Y + exact fp32 pos ----
__global__ __launch_bounds__(256) void prep_kernel(const float* __restrict__ X,
                                                   const float* __restrict__ Y,
                                                   unsigned char* __restrict__ Xf8,
                                                   unsigned char* __restrict__ Yf8,
                                                   float* __restrict__ pos,
                                                   int* __restrict__ cnt,
                                                   float* __restrict__ out) {
  if (blockIdx.x == 0) {
    if (threadIdx.x < NRB) cnt[threadIdx.x] = 0;
    if (threadIdx.x == 128) *out = 0.0f;
  }
  const int wave = threadIdx.x >> 6;
  const int lane = threadIdx.x & 63;
  const int row = blockIdx.x * 4 + wave;
  const float4* xr = (const float4*)(X + (size_t)row * C) + lane * 2;
  const float4* yr = (const float4*)(Y + (size_t)row * C) + lane * 2;
  float4 x0 = xr[0], x1 = xr[1];
  float4 y0 = yr[0], y1 = yr[1];
  float s = x0.x * y0.x + x0.y * y0.y + x0.z * y0.z + x0.w * y0.w
          + x1.x * y1.x + x1.y * y1.y + x1.z * y1.z + x1.w * y1.w;
  int2 ox, oy;
  ox.x = __builtin_amdgcn_cvt_pk_fp8_f32(x0.x, x0.y, 0, false);
  ox.x = __builtin_amdgcn_cvt_pk_fp8_f32(x0.z, x0.w, ox.x, true);
  ox.y = __builtin_amdgcn_cvt_pk_fp8_f32(x1.x, x1.y, 0, false);
  ox.y = __builtin_amdgcn_cvt_pk_fp8_f32(x1.z, x1.w, ox.y, true);
  oy.x = __builtin_amdgcn_cvt_pk_fp8_f32(y0.x, y0.y, 0, false);
  oy.x = __builtin_amdgcn_cvt_pk_fp8_f32(y0.z, y0.w, oy.x, true);
  oy.y = __builtin_amdgcn_cvt_pk_fp8_f32(y1.x, y1.y, 0, false);
  oy.y = __builtin_amdgcn_cvt_pk_fp8_f32(y1.z, y1.w, oy.y, true);
  ((int2*)(Xf8 + (size_t)row * C))[lane] = ox;
  ((int2*)(Yf8 + (size_t)row * C))[lane] = oy;
#pragma unroll
  for (int off = 32; off >= 1; off >>= 1) s += __shfl_xor(s, off);
  if (lane == 0) pos[row] = s * INV_T;
}

// ---- main: MX-scaled fp8 MFMA + base-2 online lse + fused combine ----
// v8 = v7 (PASSED, but spilled ~21 regs under the (256,2) cap -> 22MB scratch
// writes, MfmaUtil 7.5%) with 32 regs cut: m and l state packed as bf16
// pairs. m kept bf16-EXACT (new max truncated to bf16 before use) so all
// exp2 args are exact f32 algebra; truncation only costs l-range (<= 2^16,
// fine in bf16). Demand ~230 < 256 -> no spills -> verified pipeline runs.
__global__ __launch_bounds__(256, 2) void gemm_lse_kernel(const unsigned char* __restrict__ Xf8,
                                                          const unsigned char* __restrict__ Yf8,
                                                          float2* __restrict__ partials,
                                                          const float* __restrict__ pos,
                                                          int* __restrict__ cnt,
                                                          float* __restrict__ out) {
  __shared__ unsigned char Bs[2][BN][BKF];   // 32 KB double-buffered B k-tile
  __shared__ float wsum[4];
  __shared__ int mflag;

  const int tid = threadIdx.x;
  const int bx = blockIdx.x;
  const int split = bx & (NSPLIT - 1);      // XCD = bx%8 -> Y-slice L2 local
  const int rb = bx >> 3;                   // 0..127
  const int row0 = rb * BM;
  const int colbase = split * COLS_PER_SPLIT;

  const int w = tid >> 6;                   // wave 0..3 = col-slice wc
  const int lane = tid & 63;
  const int lrow = lane & 31;
  const int h = lane >> 5;                  // k-half selector
  const int swz = lrow & 7;
  const int brow = w * 32 + lrow;           // this wave's B rows in Bs

  // ---- A: 2 rowsets x full K=512, straight into fragment regs ----
  i32x8 aF0[8], aF1[8];
  {
    const unsigned char* a0 = Xf8 + (size_t)(row0 + lrow) * C + h * 32;
#pragma unroll
    for (int kk = 0; kk < 8; ++kk) {
      aF0[kk] = *(const i32x8*)(a0 + kk * 64);
      aF1[kk] = *(const i32x8*)(a0 + (size_t)32 * C + kk * 64);
    }
  }

  // B staging-lane invariants (pre-swizzled global source, linear LDS dest)
  const int r_base = tid >> 3;              // row within 32-row group
  const int p = tid & 7;
  const int j = p ^ (r_base & 7);
  const unsigned char* ybase = Yf8 + (size_t)r_base * C + (size_t)(j * 16);

  auto stageB = [&](int buf, int col0, int k0) {
#pragma unroll
    for (int i = 0; i < 4; ++i) {
      const unsigned char* gb = ybase + (size_t)(col0 + i * 32) * C + k0 * BKF;
      uint32_t loff = (uint32_t)((i * 256 + (tid & ~63)) * 16);
      __builtin_amdgcn_global_load_lds(
          (const __attribute__((address_space(1))) uint32_t*)(uintptr_t)gb,
          (__attribute__((address_space(3))) uint32_t*)(uintptr_t)((char*)&Bs[buf][0][0] + loff),
          16, 0, 0);
    }
  };

  // prologue: stage (ct=0,k0=0), then ONE real __syncthreads(): compiler
  // drains its tracked A loads + the stage loads here, pre-loop.
  stageB(0, colbase, 0);
  __syncthreads();
  __builtin_amdgcn_sched_barrier(0);

  // base-2 online state, bf16-packed (low16 = even row, high16 = odd row)
  uint32_t mpk0[8], lpk0[8], mpk1[8], lpk1[8];
#pragma unroll
  for (int s = 0; s < 8; ++s) {
    mpk0[s] = 0xFF80FF80u; lpk0[s] = 0u;    // two bf16 -inf | two bf16 zeros
    mpk1[s] = 0xFF80FF80u; lpk1[s] = 0u;
  }

  for (int ct = 0; ct < CT; ++ct) {
    f32x16 acc0, acc1;
#pragma unroll
    for (int e = 0; e < 16; ++e) { acc0[e] = 0.0f; acc1[e] = 0.0f; }

#pragma unroll
    for (int k0 = 0; k0 < 4; ++k0) {      // tile (ct,k0) lives in Bs[k0&1]
      const int nct = (k0 == 3) ? ((ct + 1) & (CT - 1)) : ct;
      const int nk0 = (k0 + 1) & 3;
      stageB((k0 + 1) & 1, colbase + nct * BN, nk0);
      __builtin_amdgcn_sched_barrier(0);
      asm volatile("s_waitcnt vmcnt(4)" ::: "memory");   // counted, never 0
      __builtin_amdgcn_s_barrier();
      __builtin_amdgcn_sched_barrier(0);

      __builtin_amdgcn_s_setprio(1);
      const unsigned char* bbase = &Bs[k0 & 1][brow][0];
#pragma unroll
      for (int s = 0; s < 2; ++s) {       // two K=64 steps per 128B segment
        const int kk = 2 * k0 + s;
        const int c0 = 4 * s + 2 * h;
        i32x8 bf;
        *(i32x4*)&bf         = *(const i32x4*)(bbase + ((c0    ) ^ swz) * 16);
        *(((i32x4*)&bf) + 1) = *(const i32x4*)(bbase + ((c0 + 1) ^ swz) * 16);
        acc0 = __builtin_amdgcn_mfma_scale_f32_32x32x64_f8f6f4(
            aF0[kk], bf, acc0, 0, 0, 0, 127, 0, 127);
        acc1 = __builtin_amdgcn_mfma_scale_f32_32x32x64_f8f6f4(
            aF1[kk], bf, acc1, 0, 0, 0, 127, 0, 127);
      }
      __builtin_amdgcn_s_setprio(0);
      __builtin_amdgcn_sched_barrier(0);
      __builtin_amdgcn_s_barrier();       // reads done before next overwrite
      __builtin_amdgcn_sched_barrier(0);
    }

    // per-lane base-2 online update; state in bf16 pairs, math in f32.
    // m kept bf16-exact: n truncated to bf16 BEFORE use, so (m - n) and
    // (u - n) are exact; truncation only inflates l by <= 2^16.
#pragma unroll
    for (int rp = 0; rp < 8; ++rp) {
      {
        float ue = acc0[2 * rp]     * SCALE2;
        float uo = acc0[2 * rp + 1] * SCALE2;
        float me = __uint_as_float(mpk0[rp] << 16);
        float mo = __uint_as_float(mpk0[rp] & 0xffff0000u);
        float le = __uint_as_float(lpk0[rp] << 16);
        float lo = __uint_as_float(lpk0[rp] & 0xffff0000u);
        float ne = __uint_as_float(__float_as_uint(fmaxf(me, ue)) & 0xffff0000u);
        float no = __uint_as_float(__float_as_uint(fmaxf(mo, uo)) & 0xffff0000u);
        le = le * exp2f(me - ne) + exp2f(ue - ne);
        lo = lo * exp2f(mo - no) + exp2f(uo - no);
        mpk0[rp] = (__float_as_uint(ne) >> 16) | (__float_as_uint(no) & 0xffff0000u);
        lpk0[rp] = ((__float_as_uint(le) + 0x8000u) >> 16)
                 | (((__float_as_uint(lo) + 0x8000u) >> 16) << 16);
      }
      {
        float ue = acc1[2 * rp]     * SCALE2;
        float uo = acc1[2 * rp + 1] * SCALE2;
        float me = __uint_as_float(mpk1[rp] << 16);
        float mo = __uint_as_float(mpk1[rp] & 0xffff0000u);
        float le = __uint_as_float(lpk1[rp] << 16);
        float lo = __uint_as_float(lpk1[rp] & 0xffff0000u);
        float ne = __uint_as_float(__float_as_uint(fmaxf(me, ue)) & 0xffff0000u);
        float no = __uint_as_float(__float_as_uint(fmaxf(mo, uo)) & 0xffff0000u);
        le = le * exp2f(me - ne) + exp2f(ue - ne);
        lo = lo * exp2f(mo - no) + exp2f(uo - no);
        mpk1[rp] = (__float_as_uint(ne) >> 16) | (__float_as_uint(no) & 0xffff0000u);
        lpk1[rp] = ((__float_as_uint(le) + 0x8000u) >> 16)
                 | (((__float_as_uint(lo) + 0x8000u) >> 16) << 16);
      }
    }
  }

  // drain the dangling wrap-prefetch (it targets Bs[0]!) before Bs reuse,
  // and make sure every wave is past it before any mb2 write.
  asm volatile("s_waitcnt vmcnt(0)" ::: "memory");
  __syncthreads();

  // merge across the 32 lanes (cols) sharing each row-set; stash to dead Bs
  float2* mb2 = (float2*)&Bs[0][0][0];      // [wc][ar][h][r] = 256 float2
#pragma unroll
  for (int r = 0; r < 16; ++r) {
    uint32_t mp0 = mpk0[r >> 1], lp0 = lpk0[r >> 1];
    uint32_t mp1 = mpk1[r >> 1], lp1 = lpk1[r >> 1];
    float ma = (r & 1) ? __uint_as_float(mp0 & 0xffff0000u) : __uint_as_float(mp0 << 16);
    float la = (r & 1) ? __uint_as_float(lp0 & 0xffff0000u) : __uint_as_float(lp0 << 16);
    float mb = (r & 1) ? __uint_as_float(mp1 & 0xffff0000u) : __uint_as_float(mp1 << 16);
    float lb = (r & 1) ? __uint_as_float(lp1 & 0xffff0000u) : __uint_as_float(lp1 << 16);
#pragma unroll
    for (int off = 1; off < 32; off <<= 1) {
      float mo = __shfl_xor(ma, off), lo = __shfl_xor(la, off);
      float mn = fmaxf(ma, mo);
      la = la * exp2f(ma - mn) + lo * exp2f(mo - mn);
      ma = mn;
      float mo2 = __shfl_xor(mb, off), lo2 = __shfl_xor(lb, off);
      float mn2 = fmaxf(mb, mo2);
      lb = lb * exp2f(mb - mn2) + lo2 * exp2f(mo2 - mn2);
      mb = mn2;
    }
    if (lrow == 0) {
      mb2[((w * 2 + 0) * 2 + h) * 16 + r] = make_float2(ma, la);
      mb2[((w * 2 + 1) * 2 + h) * 16 + r] = make_float2(mb, lb);
    }
  }
  __syncthreads();
  if (tid < BM) {                           // one thread per row
    const int ar = tid >> 5;
    const int rl = tid & 31;                // row_local = (r&3)+8*(r>>2)+4*h
    const int hI = (rl >> 2) & 1;
    const int rI = (rl & 3) + 4 * (rl >> 3);
    float M = -INFINITY, L = 0.0f;
#pragma unroll
    for (int wcI = 0; wcI < 4; ++wcI) {
      float2 pr = mb2[((wcI * 2 + ar) * 2 + hI) * 16 + rI];
      float mn = fmaxf(M, pr.x);
      L = L * exp2f(M - mn) + pr.y * exp2f(pr.x - mn);
      M = mn;
    }
    partials[(size_t)split * N + (row0 + tid)] = make_float2(M, L);
  }

  // ---- fused combine: last block for this rb merges all NSPLIT partials ----
  __syncthreads();
  if (tid == 0) {
    __threadfence();
    int old = atomicAdd(&cnt[rb], 1);
    mflag = (old == NSPLIT - 1) ? 1 : 0;
  }
  __syncthreads();
  if (mflag) {
    __threadfence();
    float v = 0.0f;
    if (tid < BM) {
      const int row = row0 + tid;
      float M = -INFINITY, L = 0.0f;
#pragma unroll
      for (int s = 0; s < NSPLIT; ++s) {
        float2 pr = partials[(size_t)s * N + row];
        float mn = fmaxf(M, pr.x);
        L = L * exp2f(M - mn) + pr.y * exp2f(pr.x - mn);
        M = mn;
      }
      v = LN2F * (M + log2f(L)) - pos[row];
    }
#pragma unroll
    for (int off = 32; off >= 1; off >>= 1) v += __shfl_xor(v, off);
    if (lane == 0) wsum[w] = v;
    __syncthreads();
    if (tid == 0) atomicAdd(out, wsum[0] + wsum[1] + wsum[2] + wsum[3]);
  }
}

extern "C" void kernel_launch(void* const* d_in, const int* in_sizes, int n_in,
                              void* d_out, int out_size, void* d_ws, size_t ws_size,
                              hipStream_t stream) {
  const float* X = (const float*)d_in[0];
  const float* Y = (const float*)d_in[1];
  float* out = (float*)d_out;

  // workspace: Xf8 (4MB) | Yf8 (4MB) | partials (512KB) | pos (32KB) | cnt
  char* w = (char*)d_ws;
  unsigned char* Xf8 = (unsigned char*)w;
  unsigned char* Yf8 = Xf8 + (size_t)N * C;
  float2* partials = (float2*)(Yf8 + (size_t)N * C);
  float* pos = (float*)((char*)partials + (size_t)NSPLIT * N * sizeof(float2));
  int* cnt = (int*)(pos + N);

  prep_kernel<<<N / 4, 256, 0, stream>>>(X, Y, Xf8, Yf8, pos, cnt, out);
  gemm_lse_kernel<<<GRID_GEMM, 256, 0, stream>>>(Xf8, Yf8, partials, pos, cnt, out);
}

// Round 9
// 134.657 us; speedup vs baseline: 1.8165x; 1.6295x over previous
//
#include <hip/hip_runtime.h>
#include <stdint.h>

#define N 8192
#define C 512
#define BM 128
#define BN 128
#define BKF 128                       /* fp8 bytes per K-tile */
#define NSPLIT 8
#define COLS_PER_SPLIT (N / NSPLIT)   /* 1024 */
#define CT (COLS_PER_SPLIT / BN)      /* 8 */
#define NRB (N / BM)                  /* 64 row-bands */
#define GRID_GEMM (NRB * NSPLIT)      /* 512 = 2 blocks/CU, single round */
#define NTILES (CT * 4)               /* 32 flattened k-tiles per block */
#define INV_T 14.285714285714286f

typedef __attribute__((ext_vector_type(4)))  int   i32x4;
typedef __attribute__((ext_vector_type(8)))  int   i32x8;
typedef __attribute__((ext_vector_type(16))) float f32x16;

// ---- fused prep: fp32 -> fp8 e4m3 (HW cvt) for X and Y + exact fp32 pos ----
// Also zeroes out + the rb merge counters (verified r2/r7/r8).
__global__ __launch_bounds__(256) void prep_kernel(const float* __restrict__ X,
                                                   const float* __restrict__ Y,
                                                   unsigned char* __restrict__ Xf8,
                                                   unsigned char* __restrict__ Yf8,
                                                   float* __restrict__ pos,
                                                   int* __restrict__ cnt,
                                                   float* __restrict__ out) {
  if (blockIdx.x == 0) {
    if (threadIdx.x < NRB) cnt[threadIdx.x] = 0;
    if (threadIdx.x == 64 + NRB) *out = 0.0f;
  }
  const int wave = threadIdx.x >> 6;
  const int lane = threadIdx.x & 63;
  const int row = blockIdx.x * 4 + wave;
  const float4* xr = (const float4*)(X + (size_t)row * C) + lane * 2;
  const float4* yr = (const float4*)(Y + (size_t)row * C) + lane * 2;
  float4 x0 = xr[0], x1 = xr[1];
  float4 y0 = yr[0], y1 = yr[1];
  float s = x0.x * y0.x + x0.y * y0.y + x0.z * y0.z + x0.w * y0.w
          + x1.x * y1.x + x1.y * y1.y + x1.z * y1.z + x1.w * y1.w;
  int2 ox, oy;
  ox.x = __builtin_amdgcn_cvt_pk_fp8_f32(x0.x, x0.y, 0, false);
  ox.x = __builtin_amdgcn_cvt_pk_fp8_f32(x0.z, x0.w, ox.x, true);
  ox.y = __builtin_amdgcn_cvt_pk_fp8_f32(x1.x, x1.y, 0, false);
  ox.y = __builtin_amdgcn_cvt_pk_fp8_f32(x1.z, x1.w, ox.y, true);
  oy.x = __builtin_amdgcn_cvt_pk_fp8_f32(y0.x, y0.y, 0, false);
  oy.x = __builtin_amdgcn_cvt_pk_fp8_f32(y0.z, y0.w, oy.x, true);
  oy.y = __builtin_amdgcn_cvt_pk_fp8_f32(y1.x, y1.y, 0, false);
  oy.y = __builtin_amdgcn_cvt_pk_fp8_f32(y1.z, y1.w, oy.y, true);
  ((int2*)(Xf8 + (size_t)row * C))[lane] = ox;
  ((int2*)(Yf8 + (size_t)row * C))[lane] = oy;
#pragma unroll
  for (int off = 32; off >= 1; off >>= 1) s += __shfl_xor(s, off);
  if (lane == 0) pos[row] = s * INV_T;
}

// ---- main: MX-scaled fp8 MFMA + online lse + fused last-block combine ----
// v9 = round-1 kernel (52.5us verified: 4 waves x 32 rows, A full-K in regs
// via asm loads = 64 VGPR, acc[4] in AGPR, B XOR-swizzle) with ONE change:
// B ring buffer deepened 2 -> 4, prefetch 3 tiles ahead, vmcnt(12).
// Flattened tile index t = ct*4+k0 makes buffer indices COMPILE-TIME:
// read buf = k0, write buf = (k0+3)&3. The vmcnt wait now covers loads
// issued 3 barrier-pairs (~1800cyc) earlier -> load latency fully hidden.
__global__ __launch_bounds__(256, 2) void gemm_lse_kernel(const unsigned char* __restrict__ Xf8,
                                                          const unsigned char* __restrict__ Yf8,
                                                          float2* __restrict__ partials,
                                                          const float* __restrict__ pos,
                                                          int* __restrict__ cnt,
                                                          float* __restrict__ out) {
  __shared__ unsigned char Bs[4][BN][BKF];   // 64 KB ring-4 B k-tiles
  __shared__ float wsum[4];
  __shared__ int mflag;

  const int tid = threadIdx.x;
  const int bx = blockIdx.x;
  const int split = bx & (NSPLIT - 1);      // XCD = bx%8 -> Y-slice L2 local
  const int rb = bx >> 3;                   // 0..63
  const int row0 = rb * BM;
  const int colbase = split * COLS_PER_SPLIT;

  const int w = tid >> 6;                   // wave 0..3: rows [w*32, +32)
  const int lane = tid & 63;
  const int lrow = lane & 31;
  const int h = lane >> 5;                  // k-half selector
  const int arow = w * 32 + lrow;
  const int swz = lrow & 7;

  // A for this wave's rows, full K=512, into registers (asm: compiler's
  // waitcnt pass can't see these -> no vmcnt(0) injected in the loop)
  i32x4 tLo[8], tHi[8];
  {
    const unsigned char* abase = Xf8 + (size_t)(row0 + arow) * C + h * 32;
#pragma unroll
    for (int kk = 0; kk < 8; ++kk) {
      asm volatile("global_load_dwordx4 %0, %1, off"
                   : "=v"(tLo[kk]) : "v"(abase + kk * 64));
      asm volatile("global_load_dwordx4 %0, %1, off offset:16"
                   : "=v"(tHi[kk]) : "v"(abase + kk * 64));
    }
  }

  // B staging-lane invariants (pre-swizzled global source, linear LDS dest)
  const int r_base = tid >> 3;
  const int p = tid & 7;
  const int j = p ^ (r_base & 7);

  auto stageB = [&](int buf, int col0, int k0) {
#pragma unroll
    for (int i = 0; i < 4; ++i) {
      const int r = i * 32 + r_base;
      const unsigned char* gb = Yf8 + (size_t)(col0 + r) * C + k0 * BKF + j * 16;
      uint32_t loff = (uint32_t)(buf * (BN * BKF) + (i * 256 + (tid & ~63)) * 16);
      __builtin_amdgcn_global_load_lds(
          (const __attribute__((address_space(1))) uint32_t*)(uintptr_t)gb,
          (__attribute__((address_space(3))) uint32_t*)(uintptr_t)((char*)&Bs[0][0][0] + loff),
          16, 0, 0);
    }
  };

  // prologue: stage tiles 0,1,2 (ct=0, k0=0..2); drain EVERYTHING (incl. the
  // asm A-loads the compiler can't track) exactly once.
  stageB(0, colbase, 0);
  stageB(1, colbase, 1);
  stageB(2, colbase, 2);
  asm volatile("s_waitcnt vmcnt(0)" ::: "memory");
  __builtin_amdgcn_sched_barrier(0);
  __builtin_amdgcn_s_barrier();
  __builtin_amdgcn_sched_barrier(0);

  // pack A fragments once (temps die here; zero per-iteration packing movs)
  i32x8 aF[8];
#pragma unroll
  for (int kk = 0; kk < 8; ++kk)
    aF[kk] = (i32x8){ tLo[kk][0], tLo[kk][1], tLo[kk][2], tLo[kk][3],
                      tHi[kk][0], tHi[kk][1], tHi[kk][2], tHi[kk][3] };

  float m_s[16], l_s[16];
#pragma unroll
  for (int s = 0; s < 16; ++s) { m_s[s] = -INFINITY; l_s[s] = 0.0f; }

  for (int ct = 0; ct < CT; ++ct) {
    f32x16 acc[4];
#pragma unroll
    for (int t = 0; t < 4; ++t)
#pragma unroll
      for (int e = 0; e < 16; ++e) acc[t][e] = 0.0f;

#pragma unroll
    for (int k0 = 0; k0 < 4; ++k0) {      // tile (ct,k0) lives in Bs[k0]
      // prefetch tile t+3 (t = ct*4+k0) into buf (k0+3)&3; clamp to last
      // tile at the tail (re-stages identical bytes into a dead buffer).
      const int tl3 = ct * 4 + k0 + 3;
      const int tl = (tl3 < NTILES - 1) ? tl3 : (NTILES - 1);
      stageB((k0 + 3) & 3, colbase + (tl >> 2) * BN, tl & 3);
      __builtin_amdgcn_sched_barrier(0);
      // wait for tile t's 4 loads (issued 3 steps ago); 12 = 3 tiles in
      // flight stay outstanding across the barrier — counted, never 0.
      asm volatile("s_waitcnt vmcnt(12)" ::: "memory");
      __builtin_amdgcn_s_barrier();
      __builtin_amdgcn_sched_barrier(0);

      __builtin_amdgcn_s_setprio(1);
#pragma unroll
      for (int s = 0; s < 2; ++s) {       // two K=64 steps per 128B segment
        const int kk = 2 * k0 + s;
        const int c0 = 4 * s + 2 * h;
#pragma unroll
        for (int tj = 0; tj < 4; ++tj) {
          const int brow = tj * 32 + lrow;
          i32x8 bf;
          *(i32x4*)&bf =
              *(const i32x4*)&Bs[k0][brow][((c0    ) ^ swz) * 16];
          *(((i32x4*)&bf) + 1) =
              *(const i32x4*)&Bs[k0][brow][((c0 + 1) ^ swz) * 16];
          acc[tj] = __builtin_amdgcn_mfma_scale_f32_32x32x64_f8f6f4(
              aF[kk], bf, acc[tj], 0, 0, 0, 127, 0, 127);
        }
      }
      __builtin_amdgcn_s_setprio(0);
      __builtin_amdgcn_sched_barrier(0);
      __builtin_amdgcn_s_barrier();       // reads done before next overwrite
      __builtin_amdgcn_sched_barrier(0);
    }

    // per-lane online update over this 128-col tile
#pragma unroll
    for (int r = 0; r < 16; ++r) {
      float v0 = acc[0][r] * INV_T;
      float v1 = acc[1][r] * INV_T;
      float v2 = acc[2][r] * INV_T;
      float v3 = acc[3][r] * INV_T;
      float mx = fmaxf(fmaxf(v0, v1), fmaxf(v2, v3));
      float mn = fmaxf(m_s[r], mx);
      l_s[r] = l_s[r] * __expf(m_s[r] - mn)
             + __expf(v0 - mn) + __expf(v1 - mn) + __expf(v2 - mn) + __expf(v3 - mn);
      m_s[r] = mn;
    }
  }

  // drain the dangling tail prefetches
  asm volatile("s_waitcnt vmcnt(0)" ::: "memory");

  // merge across the 32 lanes (cols) sharing each row-set
#pragma unroll
  for (int r = 0; r < 16; ++r) {
    float m = m_s[r], l = l_s[r];
#pragma unroll
    for (int off = 1; off < 32; off <<= 1) {
      float mo = __shfl_xor(m, off);
      float lo = __shfl_xor(l, off);
      float mn = fmaxf(m, mo);
      l = l * __expf(m - mn) + lo * __expf(mo - mn);
      m = mn;
    }
    m_s[r] = m; l_s[r] = l;
  }
  // split-major partials: partials[split*N + row] (coalesced combine reads)
  if (lrow == 0) {
#pragma unroll
    for (int r = 0; r < 16; ++r) {
      int row_local = (r & 3) + 8 * (r >> 2) + 4 * h;
      partials[(size_t)split * N + (row0 + w * 32 + row_local)] =
          make_float2(m_s[r], l_s[r]);
    }
  }

  // ---- fused combine: last block for this rb merges all NSPLIT partials ----
  __syncthreads();
  if (tid == 0) {
    __threadfence();
    int old = atomicAdd(&cnt[rb], 1);
    mflag = (old == NSPLIT - 1) ? 1 : 0;
  }
  __syncthreads();
  if (mflag) {
    __threadfence();
    float v = 0.0f;
    if (tid < BM) {
      const int row = row0 + tid;
      float M = -INFINITY, L = 0.0f;
#pragma unroll
      for (int s = 0; s < NSPLIT; ++s) {
        float2 pr = partials[(size_t)s * N + row];
        float mn = fmaxf(M, pr.x);
        L = L * __expf(M - mn) + pr.y * __expf(pr.x - mn);
        M = mn;
      }
      v = M + __logf(L) - pos[row];
    }
#pragma unroll
    for (int off = 32; off >= 1; off >>= 1) v += __shfl_xor(v, off);
    if (lane == 0) wsum[w] = v;
    __syncthreads();
    if (tid == 0) atomicAdd(out, wsum[0] + wsum[1] + wsum[2] + wsum[3]);
  }
}

extern "C" void kernel_launch(void* const* d_in, const int* in_sizes, int n_in,
                              void* d_out, int out_size, void* d_ws, size_t ws_size,
                              hipStream_t stream) {
  const float* X = (const float*)d_in[0];
  const float* Y = (const float*)d_in[1];
  float* out = (float*)d_out;

  // workspace: Xf8 (4MB) | Yf8 (4MB) | partials (512KB) | pos (32KB) | cnt
  char* w = (char*)d_ws;
  unsigned char* Xf8 = (unsigned char*)w;
  unsigned char* Yf8 = Xf8 + (size_t)N * C;
  float2* partials = (float2*)(Yf8 + (size_t)N * C);
  float* pos = (float*)((char*)partials + (size_t)NSPLIT * N * sizeof(float2));
  int* cnt = (int*)(pos + N);

  prep_kernel<<<N / 4, 256, 0, stream>>>(X, Y, Xf8, Yf8, pos, cnt, out);
  gemm_lse_kernel<<<GRID_GEMM, 256, 0, stream>>>(Xf8, Yf8, partials, pos, cnt, out);
}